// Round 6
// baseline (521.961 us; speedup 1.0000x reference)
//
#include <hip/hip_runtime.h>
#include <hip/hip_bf16.h>
#include <hip/hip_fp16.h>

// GraphSAGE: 4x (mean-agg SAGEConv + ReLU) -> mean pool -> linear classifier
// N=50000, E=800000, dims 128->128->64. fp16 feature storage, fp32 accum.
// Fused per-layer kernel: gather-mean (LDS) + dual-linear MFMA (16x16x32 f16).

typedef _Float16 f16x8 __attribute__((ext_vector_type(8)));
typedef float f32x4 __attribute__((ext_vector_type(4)));

__global__ void k_deg(const int* __restrict__ tgt, int* __restrict__ deg, int E) {
  int e = blockIdx.x * blockDim.x + threadIdx.x;
  if (e < E) atomicAdd(&deg[tgt[e]], 1);
}

// --- parallel exclusive scan over deg[0..n) -> row_start, cursor, inv_deg ---
__global__ __launch_bounds__(256) void k_scan1(const int* __restrict__ deg,
                                               int* __restrict__ partial,
                                               int* __restrict__ blocksum,
                                               float* __restrict__ inv_deg, int n) {
  __shared__ int s[256];
  int tid = threadIdx.x;
  int i = blockIdx.x * 256 + tid;
  int v = (i < n) ? deg[i] : 0;
  s[tid] = v;
  __syncthreads();
  for (int off = 1; off < 256; off <<= 1) {
    int t = (tid >= off) ? s[tid - off] : 0;
    __syncthreads();
    s[tid] += t;
    __syncthreads();
  }
  if (i < n) {
    partial[i] = s[tid] - v;
    inv_deg[i] = 1.0f / fmaxf((float)v, 1.0f);
  }
  if (tid == 255) blocksum[blockIdx.x] = s[255];
}

__global__ __launch_bounds__(256) void k_scan2(int* __restrict__ blocksum, int nb) {
  __shared__ int s[256];
  int tid = threadIdx.x;
  int v = (tid < nb) ? blocksum[tid] : 0;
  s[tid] = v;
  __syncthreads();
  for (int off = 1; off < 256; off <<= 1) {
    int t = (tid >= off) ? s[tid - off] : 0;
    __syncthreads();
    s[tid] += t;
    __syncthreads();
  }
  if (tid < nb) blocksum[tid] = s[tid] - v;
}

__global__ __launch_bounds__(256) void k_scan3(const int* __restrict__ partial,
                                               const int* __restrict__ blocksum,
                                               int* __restrict__ row_start,
                                               int* __restrict__ cursor, int n, int E) {
  int i = blockIdx.x * 256 + threadIdx.x;
  if (i < n) {
    int r = partial[i] + blocksum[blockIdx.x];
    row_start[i] = r;
    cursor[i] = r;
  }
  if (i == 0) row_start[n] = E;
}

__global__ void k_scatter(const int* __restrict__ src, const int* __restrict__ tgt,
                          int* __restrict__ cursor, int* __restrict__ csr_src, int E) {
  int e = blockIdx.x * blockDim.x + threadIdx.x;
  if (e < E) {
    int t = tgt[e];
    int pos = atomicAdd(&cursor[t], 1);
    csr_src[pos] = src[e];
  }
}

// x fp32 -> fp16, 8 elements/thread
__global__ __launch_bounds__(256) void k_cvt_x(const float* __restrict__ x,
                                               __half* __restrict__ xh, int total8) {
  int i = blockIdx.x * 256 + threadIdx.x;
  if (i >= total8) return;
  const float4* p = (const float4*)(x + (size_t)i * 8);
  float4 v0 = p[0], v1 = p[1];
  f16x8 o;
  o[0] = (_Float16)v0.x; o[1] = (_Float16)v0.y; o[2] = (_Float16)v0.z; o[3] = (_Float16)v0.w;
  o[4] = (_Float16)v1.x; o[5] = (_Float16)v1.y; o[6] = (_Float16)v1.z; o[7] = (_Float16)v1.w;
  *(f16x8*)(xh + (size_t)i * 8) = o;
}

struct WPack {
  const float* s[4];
  const float* n[4];
};

// Wt[layer][n][k] (k in [0,256): k<128 -> Ws[k][n], else Wn[k-128][n]), fp16
__global__ __launch_bounds__(256) void k_prep_w(WPack p, __half* __restrict__ Wt) {
  int l = blockIdx.y;
  int i = blockIdx.x * 256 + threadIdx.x;  // [0, 32768)
  int n = i >> 8;
  int k = i & 255;
  const float* W = (k < 128) ? p.s[l] : p.n[l];
  float v = W[(size_t)(k & 127) * 128 + n];
  Wt[(size_t)l * 32768 + (size_t)n * 256 + k] = __float2half(v);
}

// Fused SAGE layer: block = 256 threads (4 waves), 32 nodes.
// Phase 1: wave w gathers mean for nodes m0+w*8 .. +7 into LDS (2 dims/lane,
//          unroll-8 for MLP). Phase 2: MFMA out = relu([h|agg]@Wt + b).
// Wave w in phase 2: row-tile rt=w&1 (16 rows), col-half ch=w>>1 (64 cols).
__global__ __launch_bounds__(256) void k_sage(
    const __half* __restrict__ h, const int* __restrict__ csr_src,
    const int* __restrict__ row_start, const float* __restrict__ inv_deg,
    const __half* __restrict__ Wt, const float* __restrict__ bias,
    __half* __restrict__ out, int n_nodes) {
  __shared__ _Float16 aggS[32][136];  // 272B row stride (16B-aligned, bank-rotated)
  int tid = threadIdx.x;
  int wave = tid >> 6;
  int lane = tid & 63;
  int m0 = blockIdx.x * 32;

  // ---- phase 1: gather-mean ----
  {
    int lane2 = lane * 2;
    for (int i = 0; i < 8; ++i) {
      int node = m0 + wave * 8 + i;
      float a0 = 0.f, a1 = 0.f, wgt = 0.f;
      if (node < n_nodes) {
        int beg = row_start[node];
        int end = row_start[node + 1];
        wgt = inv_deg[node];
        int e = beg;
        for (; e + 7 < end; e += 8) {
          int s0 = csr_src[e + 0], s1 = csr_src[e + 1];
          int s2 = csr_src[e + 2], s3 = csr_src[e + 3];
          int s4 = csr_src[e + 4], s5 = csr_src[e + 5];
          int s6 = csr_src[e + 6], s7 = csr_src[e + 7];
          __half2 v0 = *(const __half2*)(h + (size_t)s0 * 128 + lane2);
          __half2 v1 = *(const __half2*)(h + (size_t)s1 * 128 + lane2);
          __half2 v2 = *(const __half2*)(h + (size_t)s2 * 128 + lane2);
          __half2 v3 = *(const __half2*)(h + (size_t)s3 * 128 + lane2);
          __half2 v4 = *(const __half2*)(h + (size_t)s4 * 128 + lane2);
          __half2 v5 = *(const __half2*)(h + (size_t)s5 * 128 + lane2);
          __half2 v6 = *(const __half2*)(h + (size_t)s6 * 128 + lane2);
          __half2 v7 = *(const __half2*)(h + (size_t)s7 * 128 + lane2);
          float2 f0 = __half22float2(v0), f1 = __half22float2(v1);
          float2 f2 = __half22float2(v2), f3 = __half22float2(v3);
          float2 f4 = __half22float2(v4), f5 = __half22float2(v5);
          float2 f6 = __half22float2(v6), f7 = __half22float2(v7);
          a0 += ((f0.x + f1.x) + (f2.x + f3.x)) + ((f4.x + f5.x) + (f6.x + f7.x));
          a1 += ((f0.y + f1.y) + (f2.y + f3.y)) + ((f4.y + f5.y) + (f6.y + f7.y));
        }
        for (; e < end; ++e) {
          int s0 = csr_src[e];
          float2 f0 = __half22float2(*(const __half2*)(h + (size_t)s0 * 128 + lane2));
          a0 += f0.x;
          a1 += f0.y;
        }
      }
      __half2 r;
      r.x = __float2half(a0 * wgt);
      r.y = __float2half(a1 * wgt);
      *(__half2*)&aggS[wave * 8 + i][lane2] = r;
    }
  }
  __syncthreads();

  // ---- phase 2: dual-linear MFMA ----
  int rt = wave & 1;   // row tile: rows rt*16..rt*16+15 of this block
  int ch = wave >> 1;  // col half: cols ch*64..ch*64+63
  int lr = lane & 15;
  int lg = lane >> 4;
  f32x4 acc[4];
#pragma unroll
  for (int ct = 0; ct < 4; ++ct) acc[ct] = (f32x4){0.f, 0.f, 0.f, 0.f};

  int arow = m0 + rt * 16 + lr;
  if (arow >= n_nodes) arow = n_nodes - 1;
  const __half* hrow = h + (size_t)arow * 128;
  const _Float16* grow = &aggS[rt * 16 + lr][0];

#pragma unroll
  for (int ks = 0; ks < 8; ++ks) {
    int koff = (ks & 3) * 32 + lg * 8;
    f16x8 a;
    if (ks < 4)
      a = *(const f16x8*)(hrow + koff);
    else
      a = *(const f16x8*)(grow + koff);
    int kb = ks * 32 + lg * 8;
#pragma unroll
    for (int ct = 0; ct < 4; ++ct) {
      int n_col = ch * 64 + ct * 16 + lr;
      f16x8 b = *(const f16x8*)(Wt + (size_t)n_col * 256 + kb);
      acc[ct] = __builtin_amdgcn_mfma_f32_16x16x32_f16(a, b, acc[ct], 0, 0, 0);
    }
  }

#pragma unroll
  for (int ct = 0; ct < 4; ++ct) {
    int n_col = ch * 64 + ct * 16 + lr;
    float bv = bias[n_col];
#pragma unroll
    for (int r = 0; r < 4; ++r) {
      int m = m0 + rt * 16 + lg * 4 + r;
      if (m < n_nodes)
        out[(size_t)m * 128 + n_col] = __float2half(fmaxf(acc[ct][r] + bv, 0.f));
    }
  }
}

// 256 blocks x 256 threads; wave w handles rows blk*4+w (stride 1024), lane owns
// 2 dims via half2; LDS reduce across the 4 waves -> partial[blk][128].
__global__ __launch_bounds__(256) void k_pool(const __half* __restrict__ h,
                                              float* __restrict__ partial, int n_nodes) {
  __shared__ float red[4][128];
  int tid = threadIdx.x;
  int lane = tid & 63;
  int w = tid >> 6;
  float a0 = 0.f, a1 = 0.f;
  for (int n = blockIdx.x * 4 + w; n < n_nodes; n += gridDim.x * 4) {
    float2 f = __half22float2(*(const __half2*)(h + (size_t)n * 128 + lane * 2));
    a0 += f.x;
    a1 += f.y;
  }
  red[w][lane * 2] = a0;
  red[w][lane * 2 + 1] = a1;
  __syncthreads();
  if (tid < 128) {
    partial[(size_t)blockIdx.x * 128 + tid] =
        (red[0][tid] + red[1][tid]) + (red[2][tid] + red[3][tid]);
  }
}

// 512 threads: chunked parallel reduce of partial[256][128] -> g[128], then
// chunked classifier dot g@Wc[128][64] + bc. Max serial chain: 64 loads.
__global__ __launch_bounds__(512) void k_final(const float* __restrict__ partial,
                                               const float* __restrict__ Wc,
                                               const float* __restrict__ bc,
                                               float* __restrict__ out, int n_nodes) {
  __shared__ float red[4][128];
  __shared__ float gs[128];
  __shared__ float red2[8][64];
  int tid = threadIdx.x;
  int j = tid & 127;
  int c = tid >> 7;  // 4 chunks of 64 partials
  float s = 0.f;
#pragma unroll
  for (int b = 0; b < 64; ++b) s += partial[(size_t)(c * 64 + b) * 128 + j];
  red[c][j] = s;
  __syncthreads();
  if (tid < 128) {
    float g = (red[0][tid] + red[1][tid]) + (red[2][tid] + red[3][tid]);
    gs[tid] = g / (float)n_nodes;
  }
  __syncthreads();
  {
    int jo = tid & 63;
    int c2 = tid >> 6;  // 8 chunks of 16 k
    float s2 = 0.f;
#pragma unroll
    for (int d = 0; d < 16; ++d)
      s2 += gs[c2 * 16 + d] * Wc[(size_t)(c2 * 16 + d) * 64 + jo];
    red2[c2][jo] = s2;
  }
  __syncthreads();
  if (tid < 64) {
    float o = bc[tid];
#pragma unroll
    for (int c2 = 0; c2 < 8; ++c2) o += red2[c2][tid];
    out[tid] = o;
  }
}

extern "C" void kernel_launch(void* const* d_in, const int* in_sizes, int n_in,
                              void* d_out, int out_size, void* d_ws, size_t ws_size,
                              hipStream_t stream) {
  const float* x = (const float*)d_in[0];
  const int* ei = (const int*)d_in[1];
  const float* Ws11 = (const float*)d_in[2];
  const float* Wn11 = (const float*)d_in[3];
  const float* b11 = (const float*)d_in[4];
  const float* Ws12 = (const float*)d_in[5];
  const float* Wn12 = (const float*)d_in[6];
  const float* b12 = (const float*)d_in[7];
  const float* Ws21 = (const float*)d_in[8];
  const float* Wn21 = (const float*)d_in[9];
  const float* b21 = (const float*)d_in[10];
  const float* Ws22 = (const float*)d_in[11];
  const float* Wn22 = (const float*)d_in[12];
  const float* b22 = (const float*)d_in[13];
  const float* Wc = (const float*)d_in[14];
  const float* bc = (const float*)d_in[15];

  int N = in_sizes[0] / 128;
  int E = in_sizes[1] / 2;
  const int* src = ei;
  const int* tgt = ei + E;

  // workspace layout (256B-aligned chunks)
  char* w = (char*)d_ws;
  size_t off = 0;
  auto alloc = [&](size_t bytes) {
    void* p = w + off;
    off += (bytes + 255) & ~(size_t)255;
    return p;
  };
  __half* xh = (__half*)alloc((size_t)N * 128 * 2);
  __half* hA = (__half*)alloc((size_t)N * 128 * 2);
  __half* hB = (__half*)alloc((size_t)N * 128 * 2);
  __half* Wt = (__half*)alloc((size_t)4 * 32768 * 2);
  float* partial = (float*)alloc((size_t)256 * 128 * 4);
  float* inv_deg = (float*)alloc((size_t)N * 4);
  int* deg = (int*)alloc((size_t)N * 4);
  int* row_start = (int*)alloc((size_t)(N + 1) * 4);
  int* cursor = (int*)alloc((size_t)N * 4);
  int* csr_src = (int*)alloc((size_t)E * 4);
  int* scanp = (int*)alloc((size_t)N * 4);
  int* blocksum = (int*)alloc((size_t)256 * 4);

  hipMemsetAsync(deg, 0, (size_t)N * 4, stream);
  hipMemsetAsync(partial, 0, (size_t)256 * 128 * 4, stream);
  int eb = (E + 255) / 256;
  int nb = (N + 255) / 256;
  k_deg<<<eb, 256, 0, stream>>>(tgt, deg, E);
  k_scan1<<<nb, 256, 0, stream>>>(deg, scanp, blocksum, inv_deg, N);
  k_scan2<<<1, 256, 0, stream>>>(blocksum, nb);
  k_scan3<<<nb, 256, 0, stream>>>(scanp, blocksum, row_start, cursor, N, E);
  k_scatter<<<eb, 256, 0, stream>>>(src, tgt, cursor, csr_src, E);

  int total8 = N * 128 / 8;
  k_cvt_x<<<(total8 + 255) / 256, 256, 0, stream>>>(x, xh, total8);
  WPack wp;
  wp.s[0] = Ws11; wp.s[1] = Ws12; wp.s[2] = Ws21; wp.s[3] = Ws22;
  wp.n[0] = Wn11; wp.n[1] = Wn12; wp.n[2] = Wn21; wp.n[3] = Wn22;
  k_prep_w<<<dim3(128, 4), 256, 0, stream>>>(wp, Wt);

  int sb = (N + 31) / 32;  // k_sage: 32 nodes/block

  // layer 1: xh -> hA
  k_sage<<<sb, 256, 0, stream>>>(xh, csr_src, row_start, inv_deg, Wt + 0 * 32768, b11, hA, N);
  // layer 2: hA -> hB
  k_sage<<<sb, 256, 0, stream>>>(hA, csr_src, row_start, inv_deg, Wt + 1 * 32768, b12, hB, N);
  // layer 3: hB -> hA
  k_sage<<<sb, 256, 0, stream>>>(hB, csr_src, row_start, inv_deg, Wt + 2 * 32768, b21, hA, N);
  // layer 4: hA -> hB
  k_sage<<<sb, 256, 0, stream>>>(hA, csr_src, row_start, inv_deg, Wt + 3 * 32768, b22, hB, N);

  k_pool<<<256, 256, 0, stream>>>(hB, partial, N);
  k_final<<<1, 512, 0, stream>>>(partial, Wc, bc, (float*)d_out, N);
}

// Round 7
// 416.964 us; speedup vs baseline: 1.2518x; 1.2518x over previous
//
#include <hip/hip_runtime.h>
#include <hip/hip_bf16.h>
#include <hip/hip_fp16.h>

// GraphSAGE: 4x (mean-agg SAGEConv + ReLU) -> mean pool -> linear classifier
// N=50000, E=800000, dims 128->128->64. fp16 feature storage, fp32 accum,
// MFMA (16x16x32 f16) for the dual linear layers. Separate gather + linear
// kernels (fusion regressed: occupancy + per-block straggler serialization).

typedef _Float16 f16x8 __attribute__((ext_vector_type(8)));
typedef _Float16 f16x4 __attribute__((ext_vector_type(4)));
typedef float f32x4 __attribute__((ext_vector_type(4)));

__global__ void k_deg(const int* __restrict__ tgt, int* __restrict__ deg, int E) {
  int e = blockIdx.x * blockDim.x + threadIdx.x;
  if (e < E) atomicAdd(&deg[tgt[e]], 1);
}

// --- parallel exclusive scan over deg[0..n) -> row_start, cursor, inv_deg ---
__global__ __launch_bounds__(256) void k_scan1(const int* __restrict__ deg,
                                               int* __restrict__ partial,
                                               int* __restrict__ blocksum,
                                               float* __restrict__ inv_deg, int n) {
  __shared__ int s[256];
  int tid = threadIdx.x;
  int i = blockIdx.x * 256 + tid;
  int v = (i < n) ? deg[i] : 0;
  s[tid] = v;
  __syncthreads();
  for (int off = 1; off < 256; off <<= 1) {
    int t = (tid >= off) ? s[tid - off] : 0;
    __syncthreads();
    s[tid] += t;
    __syncthreads();
  }
  if (i < n) {
    partial[i] = s[tid] - v;
    inv_deg[i] = 1.0f / fmaxf((float)v, 1.0f);
  }
  if (tid == 255) blocksum[blockIdx.x] = s[255];
}

__global__ __launch_bounds__(256) void k_scan2(int* __restrict__ blocksum, int nb) {
  __shared__ int s[256];
  int tid = threadIdx.x;
  int v = (tid < nb) ? blocksum[tid] : 0;
  s[tid] = v;
  __syncthreads();
  for (int off = 1; off < 256; off <<= 1) {
    int t = (tid >= off) ? s[tid - off] : 0;
    __syncthreads();
    s[tid] += t;
    __syncthreads();
  }
  if (tid < nb) blocksum[tid] = s[tid] - v;
}

__global__ __launch_bounds__(256) void k_scan3(const int* __restrict__ partial,
                                               const int* __restrict__ blocksum,
                                               int* __restrict__ row_start,
                                               int* __restrict__ cursor, int n, int E) {
  int i = blockIdx.x * 256 + threadIdx.x;
  if (i < n) {
    int r = partial[i] + blocksum[blockIdx.x];
    row_start[i] = r;
    cursor[i] = r;
  }
  if (i == 0) row_start[n] = E;
}

__global__ void k_scatter(const int* __restrict__ src, const int* __restrict__ tgt,
                          int* __restrict__ cursor, int* __restrict__ csr_src, int E) {
  int e = blockIdx.x * blockDim.x + threadIdx.x;
  if (e < E) {
    int t = tgt[e];
    int pos = atomicAdd(&cursor[t], 1);
    csr_src[pos] = src[e];
  }
}

// x fp32 -> fp16, 8 elements/thread
__global__ __launch_bounds__(256) void k_cvt_x(const float* __restrict__ x,
                                               __half* __restrict__ xh, int total8) {
  int i = blockIdx.x * 256 + threadIdx.x;
  if (i >= total8) return;
  const float4* p = (const float4*)(x + (size_t)i * 8);
  float4 v0 = p[0], v1 = p[1];
  f16x8 o;
  o[0] = (_Float16)v0.x; o[1] = (_Float16)v0.y; o[2] = (_Float16)v0.z; o[3] = (_Float16)v0.w;
  o[4] = (_Float16)v1.x; o[5] = (_Float16)v1.y; o[6] = (_Float16)v1.z; o[7] = (_Float16)v1.w;
  *(f16x8*)(xh + (size_t)i * 8) = o;
}

struct WPack {
  const float* s[4];
  const float* n[4];
};

// Wt[layer][n][k] (k in [0,256): k<128 -> Ws[k][n], else Wn[k-128][n]), fp16
__global__ __launch_bounds__(256) void k_prep_w(WPack p, __half* __restrict__ Wt) {
  int l = blockIdx.y;
  int i = blockIdx.x * 256 + threadIdx.x;  // [0, 32768)
  int n = i >> 8;
  int k = i & 255;
  const float* W = (k < 128) ? p.s[l] : p.n[l];
  float v = W[(size_t)(k & 127) * 128 + n];
  Wt[(size_t)l * 32768 + (size_t)n * 256 + k] = __float2half(v);
}

// One wave per node. Lane-half (lane>>5) selects which edge of a pair, lane&31
// selects 4 dims (f16x4 = 8B/lane -> each edge row = 32 lanes x 8B = 256B).
// Unroll 4 pairs -> 8 rows in flight per wave. Even/odd-edge partials are
// combined with shfl_xor(32) at the end; fp32 accumulation throughout.
__global__ __launch_bounds__(256) void k_agg_h(
    const __half* __restrict__ h, const int* __restrict__ csr_src,
    const int* __restrict__ row_start, const float* __restrict__ inv_deg,
    __half* __restrict__ agg, int n_nodes) {
  int gw = (blockIdx.x * 256 + (int)threadIdx.x) >> 6;
  int lane = threadIdx.x & 63;
  if (gw >= n_nodes) return;
  int hf = lane >> 5;        // 0: even edge of pair, 1: odd edge
  int d4 = (lane & 31) * 4;  // dims d4..d4+3
  int beg = row_start[gw];
  int end = row_start[gw + 1];
  float a0 = 0.f, a1 = 0.f, a2 = 0.f, a3 = 0.f;
  int e = beg;
  for (; e + 7 < end; e += 8) {
    int i0 = csr_src[e + 0 + hf];
    int i1 = csr_src[e + 2 + hf];
    int i2 = csr_src[e + 4 + hf];
    int i3 = csr_src[e + 6 + hf];
    f16x4 v0 = *(const f16x4*)(h + (size_t)i0 * 128 + d4);
    f16x4 v1 = *(const f16x4*)(h + (size_t)i1 * 128 + d4);
    f16x4 v2 = *(const f16x4*)(h + (size_t)i2 * 128 + d4);
    f16x4 v3 = *(const f16x4*)(h + (size_t)i3 * 128 + d4);
    a0 += ((float)v0[0] + (float)v1[0]) + ((float)v2[0] + (float)v3[0]);
    a1 += ((float)v0[1] + (float)v1[1]) + ((float)v2[1] + (float)v3[1]);
    a2 += ((float)v0[2] + (float)v1[2]) + ((float)v2[2] + (float)v3[2]);
    a3 += ((float)v0[3] + (float)v1[3]) + ((float)v2[3] + (float)v3[3]);
  }
  for (; e + 1 < end; e += 2) {
    int i0 = csr_src[e + hf];
    f16x4 v0 = *(const f16x4*)(h + (size_t)i0 * 128 + d4);
    a0 += (float)v0[0];
    a1 += (float)v0[1];
    a2 += (float)v0[2];
    a3 += (float)v0[3];
  }
  if (e < end && hf == 0) {
    int i0 = csr_src[e];
    f16x4 v0 = *(const f16x4*)(h + (size_t)i0 * 128 + d4);
    a0 += (float)v0[0];
    a1 += (float)v0[1];
    a2 += (float)v0[2];
    a3 += (float)v0[3];
  }
  // combine even/odd halves (lane l <-> l+32 hold same dims)
  a0 += __shfl_xor(a0, 32, 64);
  a1 += __shfl_xor(a1, 32, 64);
  a2 += __shfl_xor(a2, 32, 64);
  a3 += __shfl_xor(a3, 32, 64);
  if (hf == 0) {
    float wgt = inv_deg[gw];
    f16x4 r;
    r[0] = (_Float16)(a0 * wgt);
    r[1] = (_Float16)(a1 * wgt);
    r[2] = (_Float16)(a2 * wgt);
    r[3] = (_Float16)(a3 * wgt);
    *(f16x4*)(agg + (size_t)gw * 128 + d4) = r;
  }
}

// out[m][n] = relu( h[m]@Ws + agg[m]@Wn + b ), K=256 via mfma_f32_16x16x32_f16.
// Block = 256 threads = 4 waves; wave w does rows [blk*64+w*16, +16), all 128 cols.
__global__ __launch_bounds__(256) void k_linear_mfma(
    const __half* __restrict__ h, const __half* __restrict__ agg,
    const __half* __restrict__ Wt, const float* __restrict__ bias,
    __half* __restrict__ out, int n_nodes) {
  int tid = threadIdx.x;
  int wave = tid >> 6;
  int lane = tid & 63;
  int m0 = blockIdx.x * 64 + wave * 16;
  int lr = lane & 15;
  int lg = lane >> 4;
  f32x4 acc[8];
#pragma unroll
  for (int ct = 0; ct < 8; ++ct) acc[ct] = (f32x4){0.f, 0.f, 0.f, 0.f};

  int arow = m0 + lr;
  if (arow >= n_nodes) arow = n_nodes - 1;
  const __half* hrow = h + (size_t)arow * 128;
  const __half* grow = agg + (size_t)arow * 128;

#pragma unroll
  for (int ks = 0; ks < 8; ++ks) {
    const __half* srcp = (ks < 4) ? hrow : grow;
    int koff = (ks & 3) * 32 + lg * 8;
    f16x8 a = *(const f16x8*)(srcp + koff);
    int kb = ks * 32 + lg * 8;
#pragma unroll
    for (int ct = 0; ct < 8; ++ct) {
      f16x8 b = *(const f16x8*)(Wt + (size_t)(ct * 16 + lr) * 256 + kb);
      acc[ct] = __builtin_amdgcn_mfma_f32_16x16x32_f16(a, b, acc[ct], 0, 0, 0);
    }
  }

#pragma unroll
  for (int ct = 0; ct < 8; ++ct) {
    int n_col = ct * 16 + lr;
    float bv = bias[n_col];
#pragma unroll
    for (int r = 0; r < 4; ++r) {
      int m = m0 + lg * 4 + r;
      if (m < n_nodes)
        out[(size_t)m * 128 + n_col] = __float2half(fmaxf(acc[ct][r] + bv, 0.f));
    }
  }
}

// 256 blocks x 256 threads; wave w handles rows blk*4+w (stride 1024), lane owns
// 2 dims via half2; LDS reduce across the 4 waves -> partial[blk][128].
__global__ __launch_bounds__(256) void k_pool(const __half* __restrict__ h,
                                              float* __restrict__ partial, int n_nodes) {
  __shared__ float red[4][128];
  int tid = threadIdx.x;
  int lane = tid & 63;
  int w = tid >> 6;
  float a0 = 0.f, a1 = 0.f;
  for (int n = blockIdx.x * 4 + w; n < n_nodes; n += gridDim.x * 4) {
    float2 f = __half22float2(*(const __half2*)(h + (size_t)n * 128 + lane * 2));
    a0 += f.x;
    a1 += f.y;
  }
  red[w][lane * 2] = a0;
  red[w][lane * 2 + 1] = a1;
  __syncthreads();
  if (tid < 128) {
    partial[(size_t)blockIdx.x * 128 + tid] =
        (red[0][tid] + red[1][tid]) + (red[2][tid] + red[3][tid]);
  }
}

// 512 threads: chunked parallel reduce of partial[256][128] -> g[128], then
// chunked classifier dot g@Wc[128][64] + bc. Max serial chain: 64 loads.
__global__ __launch_bounds__(512) void k_final(const float* __restrict__ partial,
                                               const float* __restrict__ Wc,
                                               const float* __restrict__ bc,
                                               float* __restrict__ out, int n_nodes) {
  __shared__ float red[4][128];
  __shared__ float gs[128];
  __shared__ float red2[8][64];
  int tid = threadIdx.x;
  int j = tid & 127;
  int c = tid >> 7;  // 4 chunks of 64 partials
  float s = 0.f;
#pragma unroll
  for (int b = 0; b < 64; ++b) s += partial[(size_t)(c * 64 + b) * 128 + j];
  red[c][j] = s;
  __syncthreads();
  if (tid < 128) {
    float g = (red[0][tid] + red[1][tid]) + (red[2][tid] + red[3][tid]);
    gs[tid] = g / (float)n_nodes;
  }
  __syncthreads();
  {
    int jo = tid & 63;
    int c2 = tid >> 6;  // 8 chunks of 16 k
    float s2 = 0.f;
#pragma unroll
    for (int d = 0; d < 16; ++d)
      s2 += gs[c2 * 16 + d] * Wc[(size_t)(c2 * 16 + d) * 64 + jo];
    red2[c2][jo] = s2;
  }
  __syncthreads();
  if (tid < 64) {
    float o = bc[tid];
#pragma unroll
    for (int c2 = 0; c2 < 8; ++c2) o += red2[c2][tid];
    out[tid] = o;
  }
}

extern "C" void kernel_launch(void* const* d_in, const int* in_sizes, int n_in,
                              void* d_out, int out_size, void* d_ws, size_t ws_size,
                              hipStream_t stream) {
  const float* x = (const float*)d_in[0];
  const int* ei = (const int*)d_in[1];
  const float* Ws11 = (const float*)d_in[2];
  const float* Wn11 = (const float*)d_in[3];
  const float* b11 = (const float*)d_in[4];
  const float* Ws12 = (const float*)d_in[5];
  const float* Wn12 = (const float*)d_in[6];
  const float* b12 = (const float*)d_in[7];
  const float* Ws21 = (const float*)d_in[8];
  const float* Wn21 = (const float*)d_in[9];
  const float* b21 = (const float*)d_in[10];
  const float* Ws22 = (const float*)d_in[11];
  const float* Wn22 = (const float*)d_in[12];
  const float* b22 = (const float*)d_in[13];
  const float* Wc = (const float*)d_in[14];
  const float* bc = (const float*)d_in[15];

  int N = in_sizes[0] / 128;
  int E = in_sizes[1] / 2;
  const int* src = ei;
  const int* tgt = ei + E;

  // workspace layout (256B-aligned chunks)
  char* w = (char*)d_ws;
  size_t off = 0;
  auto alloc = [&](size_t bytes) {
    void* p = w + off;
    off += (bytes + 255) & ~(size_t)255;
    return p;
  };
  __half* xh = (__half*)alloc((size_t)N * 128 * 2);
  __half* hA = (__half*)alloc((size_t)N * 128 * 2);
  __half* hB = (__half*)alloc((size_t)N * 128 * 2);
  __half* aggb = (__half*)alloc((size_t)N * 128 * 2);
  __half* Wt = (__half*)alloc((size_t)4 * 32768 * 2);
  float* partial = (float*)alloc((size_t)256 * 128 * 4);
  float* inv_deg = (float*)alloc((size_t)N * 4);
  int* deg = (int*)alloc((size_t)N * 4);
  int* row_start = (int*)alloc((size_t)(N + 1) * 4);
  int* cursor = (int*)alloc((size_t)N * 4);
  int* csr_src = (int*)alloc((size_t)E * 4);
  int* scanp = (int*)alloc((size_t)N * 4);
  int* blocksum = (int*)alloc((size_t)256 * 4);

  hipMemsetAsync(deg, 0, (size_t)N * 4, stream);
  hipMemsetAsync(partial, 0, (size_t)256 * 128 * 4, stream);
  int eb = (E + 255) / 256;
  int nb = (N + 255) / 256;
  k_deg<<<eb, 256, 0, stream>>>(tgt, deg, E);
  k_scan1<<<nb, 256, 0, stream>>>(deg, scanp, blocksum, inv_deg, N);
  k_scan2<<<1, 256, 0, stream>>>(blocksum, nb);
  k_scan3<<<nb, 256, 0, stream>>>(scanp, blocksum, row_start, cursor, N, E);
  k_scatter<<<eb, 256, 0, stream>>>(src, tgt, cursor, csr_src, E);

  int total8 = N * 128 / 8;
  k_cvt_x<<<(total8 + 255) / 256, 256, 0, stream>>>(x, xh, total8);
  WPack wp;
  wp.s[0] = Ws11; wp.s[1] = Ws12; wp.s[2] = Ws21; wp.s[3] = Ws22;
  wp.n[0] = Wn11; wp.n[1] = Wn12; wp.n[2] = Wn21; wp.n[3] = Wn22;
  k_prep_w<<<dim3(128, 4), 256, 0, stream>>>(wp, Wt);

  int ab = (N + 3) / 4;     // k_agg_h: 4 waves/block, 1 node/wave
  int lb = (N + 63) / 64;   // k_linear_mfma: 64 rows/block

  // layer 1: xh -> hA
  k_agg_h<<<ab, 256, 0, stream>>>(xh, csr_src, row_start, inv_deg, aggb, N);
  k_linear_mfma<<<lb, 256, 0, stream>>>(xh, aggb, Wt + 0 * 32768, b11, hA, N);
  // layer 2: hA -> hB
  k_agg_h<<<ab, 256, 0, stream>>>(hA, csr_src, row_start, inv_deg, aggb, N);
  k_linear_mfma<<<lb, 256, 0, stream>>>(hA, aggb, Wt + 1 * 32768, b12, hB, N);
  // layer 3: hB -> hA
  k_agg_h<<<ab, 256, 0, stream>>>(hB, csr_src, row_start, inv_deg, aggb, N);
  k_linear_mfma<<<lb, 256, 0, stream>>>(hB, aggb, Wt + 2 * 32768, b21, hA, N);
  // layer 4: hA -> hB
  k_agg_h<<<ab, 256, 0, stream>>>(hA, csr_src, row_start, inv_deg, aggb, N);
  k_linear_mfma<<<lb, 256, 0, stream>>>(hA, aggb, Wt + 3 * 32768, b22, hB, N);

  k_pool<<<256, 256, 0, stream>>>(hB, partial, N);
  k_final<<<1, 512, 0, stream>>>(partial, Wc, bc, (float*)d_out, N);
}